// Round 1
// baseline (204.226 us; speedup 1.0000x reference)
//
#include <hip/hip_runtime.h>
#include <math.h>

#define BATCH 16
#define CH 256
#define HW 56
#define NPIX (HW*HW)          // 3136

// ---- shared device helper: compute 4x4 tile of x_fuse = relu6(bn1(dw1(x))) * bn2(dw2(x))
// via direct global reads of the (L1/L3-resident) x1 plane. Tile at rows 4ty..4ty+3,
// cols 4tx..4tx+3 (ty,tx in 0..13).
__device__ __forceinline__ void fuse_tile(
    const float* __restrict__ plane, int ty, int tx,
    const float w1[9], const float w2[9],
    float sc1, float be1, float sc2, float be2,
    float res[4][4])
{
    const int oy = 4 * ty;
    float y1a[4][4], y2a[4][4];
    #pragma unroll
    for (int a = 0; a < 4; a++)
        #pragma unroll
        for (int e = 0; e < 4; e++) { y1a[a][e] = 0.f; y2a[a][e] = 0.f; }

    #pragma unroll
    for (int iy = 0; iy < 6; iy++) {         // input rows oy-1 .. oy+4
        const int r    = oy - 1 + iy;
        const bool rok = (r >= 0) && (r < 56);
        const int rc   = rok ? r : 0;
        float rb[12];                         // rb[m] = image col 4tx-4+m
        #pragma unroll
        for (int k = 0; k < 3; k++) {
            const int cx  = tx - 1 + k;
            const bool cv = (cx >= 0) && (cx < 14);
            const int cc2 = cv ? cx : 0;
            const bool ok = rok && cv;
            float4 v = *(const float4*)(plane + rc*56 + 4*cc2);  // always in-bounds
            rb[4*k+0] = ok ? v.x : 0.f;
            rb[4*k+1] = ok ? v.y : 0.f;
            rb[4*k+2] = ok ? v.z : 0.f;
            rb[4*k+3] = ok ? v.w : 0.f;
        }
        #pragma unroll
        for (int tyy = 0; tyy < 4; tyy++) {
            const int ky = iy - tyy;          // tap row, needs 0..2
            if (ky >= 0 && ky < 3) {
                #pragma unroll
                for (int e = 0; e < 4; e++)
                    #pragma unroll
                    for (int dj = 0; dj < 3; dj++) {
                        float xv = rb[3 + e + dj];   // image col 4tx+e+dj-1
                        y1a[tyy][e] += xv * w1[ky*3+dj];
                        y2a[tyy][e] += xv * w2[ky*3+dj];
                    }
            }
        }
    }
    #pragma unroll
    for (int tyy = 0; tyy < 4; tyy++)
        #pragma unroll
        for (int e = 0; e < 4; e++) {
            float y1 = y1a[tyy][e] * sc1 + be1;
            float y2 = y2a[tyy][e] * sc2 + be2;
            float a = fminf(fmaxf(y1, 0.f), 6.f);
            res[tyy][e] = a * y2;
        }
}

// ---------------- Kernel 1: one thread per pool cell (8x8), no LDS, no barriers ----
// grid = 784 blocks * 256 threads = 16*256*49 threads exactly. Thread g handles
// plane bc = g/49, pool cell = g%49 (cy,cx in 0..6), i.e. out rows 8cy..8cy+7,
// cols 8cx..8cx+7. Rolling 3-row register window of 16 floats (cols 8cx-4..8cx+11).
#define K1_LOAD_ROW(r, dst) do {                                                 \
    const int   rr_  = (r);                                                      \
    const bool  rok_ = ((unsigned)rr_ < 56u);                                    \
    const float* rp_ = plane + (rok_ ? rr_ : 0) * 56;                            \
    float4 a_ = *(const float4*)(rp_ + col0);                                    \
    float4 b_ = *(const float4*)(rp_ + cbase + 4);                               \
    float4 c_ = *(const float4*)(rp_ + cbase + 8);                               \
    float4 d_ = *(const float4*)(rp_ + col3);                                    \
    const bool l_ = rok_ && (cx > 0);                                            \
    const bool r_ = rok_ && (cx < 6);                                            \
    (dst)[0]=l_?a_.x:0.f;  (dst)[1]=l_?a_.y:0.f;  (dst)[2]=l_?a_.z:0.f;  (dst)[3]=l_?a_.w:0.f;   \
    (dst)[4]=rok_?b_.x:0.f;(dst)[5]=rok_?b_.y:0.f;(dst)[6]=rok_?b_.z:0.f;(dst)[7]=rok_?b_.w:0.f; \
    (dst)[8]=rok_?c_.x:0.f;(dst)[9]=rok_?c_.y:0.f;(dst)[10]=rok_?c_.z:0.f;(dst)[11]=rok_?c_.w:0.f;\
    (dst)[12]=r_?d_.x:0.f; (dst)[13]=r_?d_.y:0.f; (dst)[14]=r_?d_.z:0.f; (dst)[15]=r_?d_.w:0.f; \
} while (0)

__global__ __launch_bounds__(256) void k1_cell(
    const float* __restrict__ x1,
    const float* __restrict__ dw1w, const float* __restrict__ g1, const float* __restrict__ b1,
    const float* __restrict__ m1, const float* __restrict__ v1,
    const float* __restrict__ dw2w, const float* __restrict__ g2, const float* __restrict__ b2,
    const float* __restrict__ m2, const float* __restrict__ v2,
    float* __restrict__ pooled)  // ws: [B*C*49]
{
    const int g    = blockIdx.x * 256 + threadIdx.x;   // 0..200703
    const int bc   = g / 49;
    const int cell = g - bc * 49;
    const int c    = bc & 255;
    const int cy   = cell / 7, cx = cell - cy * 7;
    const float* plane = x1 + (size_t)bc * NPIX;

    float w1[9], w2[9];
    #pragma unroll
    for (int k = 0; k < 9; k++) { w1[k] = dw1w[c*9+k]; w2[k] = dw2w[c*9+k]; }
    const float sc1 = g1[c] * rsqrtf(v1[c] + 1e-5f);
    const float be1 = b1[c] - m1[c] * sc1;
    const float sc2 = g2[c] * rsqrtf(v2[c] + 1e-5f);
    const float be2 = b2[c] - m2[c] * sc2;

    const int rbase = 8*cy - 1;
    const int cbase = 8*cx - 4;                 // rows[s][m] <-> image col cbase+m
    const int col0  = (cx > 0) ? cbase      : 0;
    const int col3  = (cx < 6) ? cbase + 12 : 0;

    float rows[3][16];
    K1_LOAD_ROW(rbase + 0, rows[0]);
    K1_LOAD_ROW(rbase + 1, rows[1]);

    float sum = 0.f;
    #pragma unroll
    for (int yy = 0; yy < 8; yy++) {            // output row 8cy+yy
        K1_LOAD_ROW(rbase + yy + 2, rows[(yy + 2) % 3]);
        float y1[8], y2[8];
        #pragma unroll
        for (int e = 0; e < 8; e++) { y1[e] = 0.f; y2[e] = 0.f; }
        #pragma unroll
        for (int ky = 0; ky < 3; ky++) {
            const float* rr = rows[(yy + ky) % 3];   // image row rbase+yy+ky
            #pragma unroll
            for (int e = 0; e < 8; e++)
                #pragma unroll
                for (int kx = 0; kx < 3; kx++) {
                    float xv = rr[3 + e + kx];       // image col 8cx+e+kx-1
                    y1[e] += xv * w1[ky*3+kx];
                    y2[e] += xv * w2[ky*3+kx];
                }
        }
        #pragma unroll
        for (int e = 0; e < 8; e++) {
            float a = fminf(fmaxf(y1[e]*sc1 + be1, 0.f), 6.f);
            sum += a * (y2[e]*sc2 + be2);
        }
    }
    pooled[(size_t)bc * 49 + cell] = sum * (1.f/64.f);
}

// ---------------- Kernel 2a: h[b][p][o] = gelu(pw1 . pooled + pb1), p=49 is mean ----
__global__ __launch_bounds__(256) void k2a(
    const float* __restrict__ pooled, const float* __restrict__ pw1,
    const float* __restrict__ pb1, float* __restrict__ h)
{
    const int b  = blockIdx.x;
    const int oc = blockIdx.y;        // output chunk 0..3 (16 o each)
    const int t  = threadIdx.x;
    __shared__ float pl[256*50];      // 50 KB: [c][p], p=49 -> channel mean

    const float* pp = pooled + (size_t)b * 256 * 49;
    for (int idx = t; idx < 256*49; idx += 256) {
        int cc = idx / 49, p = idx - cc * 49;
        pl[cc*50 + p] = pp[idx];
    }
    __syncthreads();
    {   // per-channel mean (mean over 49 uniform block means == plane mean)
        float s = 0.f;
        #pragma unroll
        for (int p = 0; p < 49; p++) s += pl[t*50 + p];
        pl[t*50 + 49] = s * (1.f/49.f);
    }
    __syncthreads();

    for (int idx = t; idx < 16*50; idx += 256) {
        int ol = idx / 50, p = idx - ol * 50;
        int o = oc * 16 + ol;
        const float* wrow = pw1 + o * 256;
        float acc = pb1[o];
        #pragma unroll 8
        for (int cc = 0; cc < 256; cc++) acc += wrow[cc] * pl[cc*50 + p];
        float gv = 0.5f * acc * (1.f + erff(acc * 0.70710678118654752f));
        h[((size_t)b * 50 + p) * 64 + o] = gv;   // transposed layout [B][50][64]
    }
}

// ---------------- Kernel 2b: second proj + softmax over G + dynamic w/b ------------
__global__ __launch_bounds__(256) void k2b(
    const float* __restrict__ h, const float* __restrict__ pw2, const float* __restrict__ pb2,
    const float* __restrict__ weight1, const float* __restrict__ bias1,
    float* __restrict__ w_dyn, float* __restrict__ b_dyn)
{
    const int b   = blockIdx.x;
    const int cch = blockIdx.y;       // 0..15, 16 channels each
    const int t   = threadIdx.x;
    const int c_base = cch * 16;

    __shared__ __attribute__((aligned(16))) float hl[50*64];  // 12.8 KB [p][r]
    __shared__ float sl[64*51];       // 13.1 KB [row][p], row = g*16+cl

    const float* hp = h + (size_t)b * 50 * 64;
    for (int i = t; i < 800; i += 256) ((float4*)hl)[i] = ((const float4*)hp)[i];

    const int row = t & 63;           // fixed per thread
    const int pb  = t >> 6;           // 0..3
    const int g   = row >> 4, cl = row & 15;
    const int o2  = (g << 8) + c_base + cl;

    float wreg[64];
    {
        const float4* w4 = (const float4*)(pw2 + (size_t)o2 * 64);
        #pragma unroll
        for (int r4 = 0; r4 < 16; r4++) {
            float4 v = w4[r4];
            wreg[4*r4] = v.x; wreg[4*r4+1] = v.y; wreg[4*r4+2] = v.z; wreg[4*r4+3] = v.w;
        }
    }
    const float bias2 = pb2[o2];
    __syncthreads();

    for (int p = pb; p < 50; p += 4) {
        const float4* hv = (const float4*)&hl[p*64];
        float acc = bias2;
        #pragma unroll
        for (int r4 = 0; r4 < 16; r4++) {
            float4 v = hv[r4];      // broadcast across wave (same p)
            acc += wreg[4*r4]*v.x + wreg[4*r4+1]*v.y + wreg[4*r4+2]*v.z + wreg[4*r4+3]*v.w;
        }
        sl[row*51 + p] = acc;
    }
    __syncthreads();

    for (int idx = t; idx < 16*50; idx += 256) {
        int cl2 = idx / 50, p = idx - cl2 * 50;
        float s0 = sl[(cl2     )*51 + p];
        float s1 = sl[(16 + cl2)*51 + p];
        float s2 = sl[(32 + cl2)*51 + p];
        float s3 = sl[(48 + cl2)*51 + p];
        float mx = fmaxf(fmaxf(s0, s1), fmaxf(s2, s3));
        float e0 = expf(s0-mx), e1 = expf(s1-mx), e2 = expf(s2-mx), e3 = expf(s3-mx);
        float inv = 1.f / (e0+e1+e2+e3);
        e0 *= inv; e1 *= inv; e2 *= inv; e3 *= inv;
        int cc = c_base + cl2;
        if (p < 49) {
            float wv = e0*weight1[(0*256+cc)*49+p] + e1*weight1[(1*256+cc)*49+p]
                     + e2*weight1[(2*256+cc)*49+p] + e3*weight1[(3*256+cc)*49+p];
            w_dyn[((size_t)b*256 + cc)*49 + p] = wv;
        } else {
            b_dyn[b*256 + cc] = e0*bias1[cc] + e1*bias1[256+cc] + e2*bias1[512+cc] + e3*bias1[768+cc];
        }
    }
}

// ---------------- Kernel 3: recompute x_fuse into LDS halo, then dynamic 7x7 conv ----
// Waves 0-2 (threads 0..191): tiles 0..191 as 4x4 tiles (phase A fuse -> halo,
// phase B 7x7 conv). Wave 3 (threads 192..255): border zeroing (208 float4) +
// the 4 leftover tiles (192..195) at 1 pixel per lane. Single barrier.
#define S3 68
__global__ __launch_bounds__(256) void k3_dyn(
    const float* __restrict__ x1,
    const float* __restrict__ dw1w, const float* __restrict__ g1, const float* __restrict__ b1,
    const float* __restrict__ m1, const float* __restrict__ v1,
    const float* __restrict__ dw2w, const float* __restrict__ g2, const float* __restrict__ b2,
    const float* __restrict__ m2, const float* __restrict__ v2,
    const float* __restrict__ w_dyn, const float* __restrict__ b_dyn,
    float* __restrict__ out)
{
    const int bc = blockIdx.x;
    const int c  = bc & 255;
    const int t  = threadIdx.x;
    __shared__ __attribute__((aligned(16))) float halo[62*S3];  // 16.9 KB

    // block-uniform constants (scalar path)
    float w1[9], w2[9];
    #pragma unroll
    for (int k = 0; k < 9; k++) { w1[k] = dw1w[c*9+k]; w2[k] = dw2w[c*9+k]; }
    const float sc1 = g1[c] * rsqrtf(v1[c] + 1e-5f);
    const float be1 = b1[c] - m1[c] * sc1;
    const float sc2 = g2[c] * rsqrtf(v2[c] + 1e-5f);
    const float be2 = b2[c] - m2[c] * sc2;
    float wk[49];
    const float* wp = w_dyn + (size_t)bc * 49;   // block-uniform -> s_loads
    #pragma unroll
    for (int k = 0; k < 49; k++) wk[k] = wp[k];
    const float bias = b_dyn[bc];
    const float* plane = x1 + (size_t)bc * NPIX;

    const int ty = t / 14, tx = t - ty * 14;     // valid tile coords for t<192

    // ---------------- phase A ----------------
    if (t < 192) {
        float res[4][4];
        fuse_tile(plane, ty, tx, w1, w2, sc1, be1, sc2, be2, res);
        #pragma unroll
        for (int tyy = 0; tyy < 4; tyy++) {
            float4 r4; r4.x=res[tyy][0]; r4.y=res[tyy][1]; r4.z=res[tyy][2]; r4.w=res[tyy][3];
            *(float4*)&halo[(4*ty + tyy + 3)*S3 + 4 + 4*tx] = r4;
        }
    } else {
        const int lane = t - 192;                // 0..63
        // border zeroing: rows {0,1,2,59,60,61} x f4-cols 0..15, plus
        // rows 3..58 x f4-cols {0,15}. 96 + 112 = 208 float4 tasks.
        float4 z = make_float4(0.f, 0.f, 0.f, 0.f);
        for (int task = lane; task < 208; task += 64) {
            int row, c4;
            if (task < 96) { int tr = task >> 4; row = (tr < 3) ? tr : 56 + tr; c4 = task & 15; }
            else           { int m = task - 96;  row = 3 + (m >> 1); c4 = (m & 1) ? 15 : 0; }
            *(float4*)&halo[row*S3 + 4*c4] = z;
        }
        // leftover tiles 192..195 (ty=13, tx=10..13): 4 tiles * 16 px = 64 px, 1/lane
        const int tt = lane >> 4;                // 0..3
        const int p  = lane & 15;
        const int y  = 52 + (p >> 2);            // 52..55
        const int x  = 4*(10 + tt) + (p & 3);    // 40..55
        float y1 = 0.f, y2 = 0.f;
        #pragma unroll
        for (int ky = 0; ky < 3; ky++) {
            const int r  = y - 1 + ky;           // 51..56
            const bool rv = (r < 56);
            const int rc = rv ? r : 55;
            #pragma unroll
            for (int kx = 0; kx < 3; kx++) {
                const int cc2 = x - 1 + kx;      // 39..56
                const bool cv = (cc2 < 56);
                const float xv = (rv && cv) ? plane[rc*56 + (cv ? cc2 : 55)] : 0.f;
                y1 += xv * w1[ky*3+kx];
                y2 += xv * w2[ky*3+kx];
            }
        }
        float a = fminf(fmaxf(y1*sc1 + be1, 0.f), 6.f);
        halo[(y + 3)*S3 + 4 + x] = a * (y2*sc2 + be2);
    }
    __syncthreads();

    // ---------------- phase B ----------------
    if (t < 192) {
        const int oy = ty * 4, ox = tx * 4;
        float acc[4][4];
        #pragma unroll
        for (int a = 0; a < 4; a++)
            #pragma unroll
            for (int bb = 0; bb < 4; bb++) acc[a][bb] = bias;

        #pragma unroll
        for (int iy = 0; iy < 10; iy++) {
            const float* hr = &halo[(oy+iy)*S3 + ox];  // aligned
            float4 a = *(const float4*)hr;             // 3x ds_read_b128
            float4 b = *(const float4*)(hr + 4);
            float4 cc = *(const float4*)(hr + 8);
            float row[12];                             // row[m] = image col ox+m-4
            row[0]=a.x; row[1]=a.y; row[2]=a.z; row[3]=a.w;
            row[4]=b.x; row[5]=b.y; row[6]=b.z; row[7]=b.w;
            row[8]=cc.x; row[9]=cc.y; row[10]=cc.z; row[11]=cc.w;
            #pragma unroll
            for (int tyy = 0; tyy < 4; tyy++) {
                const int ky = iy - tyy;
                if (ky >= 0 && ky < 7) {
                    #pragma unroll
                    for (int txx = 0; txx < 4; txx++)
                        #pragma unroll
                        for (int kx = 0; kx < 7; kx++)
                            acc[tyy][txx] += row[1+txx+kx] * wk[ky*7+kx];
                }
            }
        }
        float* op = out + (size_t)bc * NPIX;
        #pragma unroll
        for (int tyy = 0; tyy < 4; tyy++) {
            float4 r4; r4.x = acc[tyy][0]; r4.y = acc[tyy][1]; r4.z = acc[tyy][2]; r4.w = acc[tyy][3];
            *(float4*)(op + (oy+tyy)*56 + ox) = r4;
        }
    } else {
        const int lane = t - 192;
        const int tt = lane >> 4;
        const int p  = lane & 15;
        const int y  = 52 + (p >> 2);
        const int x  = 4*(10 + tt) + (p & 3);
        float acc = bias;
        #pragma unroll
        for (int ky = 0; ky < 7; ky++)
            #pragma unroll
            for (int kx = 0; kx < 7; kx++)
                acc += halo[(y + ky)*S3 + (x + 1) + kx] * wk[ky*7+kx];
        out[(size_t)bc * NPIX + y*56 + x] = acc;
    }
}

extern "C" void kernel_launch(void* const* d_in, const int* in_sizes, int n_in,
                              void* d_out, int out_size, void* d_ws, size_t ws_size,
                              hipStream_t stream) {
    const float* x1    = (const float*)d_in[0];
    const float* dw1w  = (const float*)d_in[1];
    const float* dw1g  = (const float*)d_in[2];
    const float* dw1b  = (const float*)d_in[3];
    const float* dw1m  = (const float*)d_in[4];
    const float* dw1v  = (const float*)d_in[5];
    const float* dw2w  = (const float*)d_in[6];
    const float* dw2g  = (const float*)d_in[7];
    const float* dw2b  = (const float*)d_in[8];
    const float* dw2m  = (const float*)d_in[9];
    const float* dw2v  = (const float*)d_in[10];
    const float* weight1 = (const float*)d_in[11];
    const float* bias1   = (const float*)d_in[12];
    const float* pw1     = (const float*)d_in[13];
    const float* pb1     = (const float*)d_in[14];
    const float* pw2     = (const float*)d_in[15];
    const float* pb2     = (const float*)d_in[16];

    float* out = (float*)d_out;
    float* ws  = (float*)d_ws;
    float* pooled = ws;                    // 16*256*49 = 200,704
    float* h      = ws + 200704;           // 16*50*64  =  51,200
    float* w_dyn  = ws + 251904;           // 16*256*49 = 200,704
    float* b_dyn  = ws + 452608;           // 16*256    =   4,096

    k1_cell<<<784, 256, 0, stream>>>(x1, dw1w, dw1g, dw1b, dw1m, dw1v,
                                     dw2w, dw2g, dw2b, dw2m, dw2v, pooled);
    k2a<<<dim3(BATCH, 4), 256, 0, stream>>>(pooled, pw1, pb1, h);
    k2b<<<dim3(BATCH, 16), 256, 0, stream>>>(h, pw2, pb2, weight1, bias1, w_dyn, b_dyn);
    k3_dyn<<<BATCH*CH, 256, 0, stream>>>(x1, dw1w, dw1g, dw1b, dw1m, dw1v,
                                         dw2w, dw2g, dw2b, dw2m, dw2v,
                                         w_dyn, b_dyn, out);
}